// Round 1
// baseline (13960.120 us; speedup 1.0000x reference)
//
#include <hip/hip_runtime.h>
#include <hip/hip_cooperative_groups.h>
#include <math.h>

namespace cg = cooperative_groups;

// Problem constants (B=16, N=M=1024, D=32)
constexpr int   BB       = 16;
constexpr int   NN       = 1024;
constexpr float EPSf     = 1e-3f;
constexpr float INV_EPS  = 1.0f / 1e-3f;
constexpr int   MAX_ITER = 100;
constexpr float THRESH   = 0.1f;

// ---------------------------------------------------------------------------
// Pass 0: dist[b][p][q] = sum_d (A[b][p][d] - Bm[b][q][d])^2
// Called twice: (x,y)->C and (y,x)->CT (squared diff is symmetric).
// Block handles (b, 4 rows p); thread t covers q = t + 256k, k=0..3.
// ---------------------------------------------------------------------------
__global__ __launch_bounds__(256) void build_dist(
    const float* __restrict__ A, const float* __restrict__ Bm,
    float* __restrict__ out)
{
    const int blk = blockIdx.x;          // 16 * 256 blocks
    const int b   = blk >> 8;
    const int p0  = (blk & 255) << 2;    // 4 rows
    const int t   = threadIdx.x;

    const float4* A4 = (const float4*)(A + ((size_t)b * NN + p0) * 32);
    const float4* B4 = (const float4*)(Bm + (size_t)b * NN * 32);

    float acc[4][4];
#pragma unroll
    for (int r = 0; r < 4; ++r)
#pragma unroll
        for (int k = 0; k < 4; ++k) acc[r][k] = 0.f;

#pragma unroll
    for (int dc = 0; dc < 8; ++dc) {
        float4 a[4];
#pragma unroll
        for (int r = 0; r < 4; ++r) a[r] = A4[r * 8 + dc];
#pragma unroll
        for (int k = 0; k < 4; ++k) {
            const int q = t + (k << 8);
            float4 bq = B4[q * 8 + dc];
#pragma unroll
            for (int r = 0; r < 4; ++r) {
                float dx = a[r].x - bq.x;
                float dy = a[r].y - bq.y;
                float dz = a[r].z - bq.z;
                float dw = a[r].w - bq.w;
                acc[r][k] += dx * dx + dy * dy + dz * dz + dw * dw;
            }
        }
    }
#pragma unroll
    for (int r = 0; r < 4; ++r)
#pragma unroll
        for (int k = 0; k < 4; ++k)
            out[((size_t)b * NN + p0 + r) * NN + t + (k << 8)] = acc[r][k];
}

// Two-pass (max then sum) logsumexp over one row of 1024:
// LSE_j (vec[j] - Crow[j]) * INV_EPS, computed by one 64-lane wave
// (16 elements per lane held in registers).
__device__ __forceinline__ float lse_row(
    const float* __restrict__ Cbase, const float* lds_vec,
    int b, int row, int lane)
{
    const float4* Crow = (const float4*)(Cbase + (((size_t)b << 10) + row) * NN);
    const float4* V4   = (const float4*)lds_vec;
    float x[16];
#pragma unroll
    for (int k = 0; k < 4; ++k) {
        float4 c4 = Crow[lane + (k << 6)];
        float4 v4 = V4[lane + (k << 6)];
        x[4 * k + 0] = (v4.x - c4.x) * INV_EPS;
        x[4 * k + 1] = (v4.y - c4.y) * INV_EPS;
        x[4 * k + 2] = (v4.z - c4.z) * INV_EPS;
        x[4 * k + 3] = (v4.w - c4.w) * INV_EPS;
    }
    float m = x[0];
#pragma unroll
    for (int i = 1; i < 16; ++i) m = fmaxf(m, x[i]);
#pragma unroll
    for (int off = 32; off > 0; off >>= 1) m = fmaxf(m, __shfl_xor(m, off));
    float s = 0.f;
#pragma unroll
    for (int i = 0; i < 16; ++i) s += __expf(x[i] - m);
#pragma unroll
    for (int off = 32; off > 0; off >>= 1) s += __shfl_xor(s, off);
    return m + __logf(s);
}

// ---------------------------------------------------------------------------
// Persistent cooperative kernel: full Sinkhorn loop + final cost.
// 512 blocks x 256 threads; block -> (b = blk>>5, rows (blk&31)*32 .. +32),
// one wave per row (8 rows per wave). 2 grid.sync() per iteration.
// ---------------------------------------------------------------------------
__global__ __launch_bounds__(256, 2) void sinkhorn_kernel(
    const float* __restrict__ C, const float* __restrict__ CT,
    float* u0, float* u1, float* v,
    float* err_acc, float* cost_acc, float* out)
{
    cg::grid_group grid = cg::this_grid();
    __shared__ float lds_vec[1024];
    __shared__ float red[4];
    __shared__ float s_bcast;

    const int blk      = blockIdx.x;
    const int tid      = threadIdx.x;
    const int wave     = tid >> 6;
    const int lane     = tid & 63;
    const int b        = blk >> 5;
    const int row_base = (blk & 31) << 5;
    const float LOGK   = logf(1.0f / 1024.0f + 1e-8f);  // log_mu == log_nu

    int cur = 0;  // u ping-pong: uold = (cur? u1:u0), unew = other
    for (int it = 0; it < MAX_ITER; ++it) {
        float* uold = cur ? u1 : u0;
        float* unew = cur ? u0 : u1;

        // ---- u pass: u_new[b,i] = eps*(log_mu - LSE_j((v_j - C_ij)/eps)) ----
        ((float4*)lds_vec)[tid] = ((const float4*)(v + (b << 10)))[tid];
        __syncthreads();
        float werr = 0.f;
        for (int rr = 0; rr < 8; ++rr) {
            const int row = row_base + (wave << 3) + rr;
            float lse = lse_row(C, lds_vec, b, row, lane);
            if (lane == 0) {
                float r = EPSf * (LOGK - lse);
                werr += fabsf(r - uold[(b << 10) + row]);
                unew[(b << 10) + row] = r;
            }
        }
        if (lane == 0) red[wave] = werr;
        __syncthreads();
        if (tid == 0) atomicAdd(&err_acc[it], red[0] + red[1] + red[2] + red[3]);
        grid.sync();

        // ---- v pass: v_new[b,j] = eps*(log_nu - LSE_i((u_i - C_ij)/eps)) ----
        ((float4*)lds_vec)[tid] = ((const float4*)(unew + (b << 10)))[tid];
        __syncthreads();
        for (int rr = 0; rr < 8; ++rr) {
            const int col = row_base + (wave << 3) + rr;
            float lse = lse_row(CT, lds_vec, b, col, lane);
            if (lane == 0) v[(b << 10) + col] = EPSf * (LOGK - lse);
        }
        grid.sync();

        // ---- convergence: err = (sum_{b,i} |du|) / B, uniform across grid ----
        if (tid == 0) s_bcast = atomicAdd(&err_acc[it], 0.0f);
        __syncthreads();
        float err = s_bcast * (1.0f / 16.0f);
        cur ^= 1;
        if (err < THRESH) break;   // triggering update already applied
    }

    // ---- cost = mean_b sum_ij exp((-C+u+v)/eps) * C ----
    float* uf = cur ? u1 : u0;  // latest written u
    ((float4*)lds_vec)[tid] = ((const float4*)(v + (b << 10)))[tid];
    __syncthreads();
    float csum = 0.f;
    for (int rr = 0; rr < 8; ++rr) {
        const int row = row_base + (wave << 3) + rr;
        const float u_i = uf[(b << 10) + row];
        const float4* Crow = (const float4*)(C + (((size_t)b << 10) + row) * NN);
        const float4* V4 = (const float4*)lds_vec;
#pragma unroll
        for (int k = 0; k < 4; ++k) {
            float4 c4 = Crow[lane + (k << 6)];
            float4 v4 = V4[lane + (k << 6)];
            csum += __expf((u_i + v4.x - c4.x) * INV_EPS) * c4.x;
            csum += __expf((u_i + v4.y - c4.y) * INV_EPS) * c4.y;
            csum += __expf((u_i + v4.z - c4.z) * INV_EPS) * c4.z;
            csum += __expf((u_i + v4.w - c4.w) * INV_EPS) * c4.w;
        }
    }
#pragma unroll
    for (int off = 32; off > 0; off >>= 1) csum += __shfl_xor(csum, off);
    if (lane == 0) red[wave] = csum;
    __syncthreads();
    if (tid == 0) atomicAdd(cost_acc, red[0] + red[1] + red[2] + red[3]);
    grid.sync();
    if (blk == 0 && tid == 0)
        out[0] = atomicAdd(cost_acc, 0.0f) * (1.0f / 16.0f);
}

extern "C" void kernel_launch(void* const* d_in, const int* in_sizes, int n_in,
                              void* d_out, int out_size, void* d_ws, size_t ws_size,
                              hipStream_t stream) {
    const float* x = (const float*)d_in[0];  // output: [16,1024,32] fp32
    const float* y = (const float*)d_in[1];  // labels: [16,1024,32] fp32

    float* ws   = (float*)d_ws;
    float* C    = ws;                         // 16M floats (64 MB)
    float* CT   = ws + 16777216;              // 16M floats (64 MB)
    float* u0   = ws + 33554432;              // 16384
    float* u1   = u0 + 16384;                 // 16384
    float* v    = u1 + 16384;                 // 16384
    float* err  = v + 16384;                  // 128 (MAX_ITER=100)
    float* cost = err + 128;                  // 1
    float* out  = (float*)d_out;

    // zero u0,u1,v,err,cost (contiguous) — ws is poisoned before every call
    hipMemsetAsync(u0, 0, (size_t)(3 * 16384 + 129) * sizeof(float), stream);

    build_dist<<<dim3(BB * 256), dim3(256), 0, stream>>>(x, y, C);
    build_dist<<<dim3(BB * 256), dim3(256), 0, stream>>>(y, x, CT);

    void* args[] = {(void*)&C, (void*)&CT, (void*)&u0, (void*)&u1,
                    (void*)&v, (void*)&err, (void*)&cost, (void*)&out};
    hipLaunchCooperativeKernel((void*)sinkhorn_kernel, dim3(512), dim3(256),
                               args, 0, stream);
}

// Round 6
// 2656.992 us; speedup vs baseline: 5.2541x; 5.2541x over previous
//
#include <hip/hip_runtime.h>

// Problem constants (B=16, N=M=1024, D=32)
constexpr int   NN       = 1024;
constexpr float EPSf     = 1e-3f;
constexpr int   MAX_ITER = 100;

// exp2-domain scale: x = (v - C) * (1/eps) * log2(e)
#define K2   1442.6950408889634f
#define LN2f 0.6931471805599453f
#define LOGK (-6.9314616f)   // log(1/1024 + 1e-8)

// hardware transcendentals (avoid libm name collisions)
#define EXP2F(x) __builtin_amdgcn_exp2f(x)   // 2^x
#define LOG2F(x) __builtin_amdgcn_logf(x)    // log2(x)

// ---------------------------------------------------------------------------
// dist[b][p][q] = sum_d (A[b][p][d] - Bm[b][q][d])^2
// Block = (b, 16-row p-tile); loops 4 q-tiles of 256. B tile staged into LDS
// coalesced (row stride 33 floats -> conflict-free strided reads); each
// thread keeps its B row in 32 registers; A read via LDS float4 broadcast.
// ---------------------------------------------------------------------------
__global__ __launch_bounds__(256) void build_dist(
    const float* __restrict__ A, const float* __restrict__ Bm,
    float* __restrict__ out)
{
    __shared__ float aLds[16 * 32];
    __shared__ float bLds[256 * 33];
    const int b  = blockIdx.x >> 6;       // 16 * 64 blocks
    const int pt = blockIdx.x & 63;
    const int t  = threadIdx.x;

    const float* Ab = A  + ((size_t)b * NN + pt * 16) * 32;
    const float* Bb = Bm + (size_t)b * NN * 32;

    if (t < 128) ((float4*)aLds)[t] = ((const float4*)Ab)[t];

    for (int qt = 0; qt < 4; ++qt) {
        __syncthreads();   // aLds ready (qt=0) / bLds reuse safe (qt>0)
        const float4* src = (const float4*)(Bb + qt * 256 * 32);
#pragma unroll
        for (int i = 0; i < 8; ++i) {
            int j = t + (i << 8);                 // float4 index, coalesced
            float4 val = src[j];
            int q = j >> 3, dd = (j & 7) << 2;
            float* dst = &bLds[q * 33 + dd];
            dst[0] = val.x; dst[1] = val.y; dst[2] = val.z; dst[3] = val.w;
        }
        __syncthreads();

        float br[32];
#pragma unroll
        for (int d = 0; d < 32; ++d) br[d] = bLds[t * 33 + d];

#pragma unroll
        for (int p = 0; p < 16; ++p) {
            float acc = 0.f;
#pragma unroll
            for (int d4 = 0; d4 < 8; ++d4) {
                float4 a4 = ((const float4*)(aLds + p * 32))[d4];
                float dx = a4.x - br[d4 * 4 + 0];
                float dy = a4.y - br[d4 * 4 + 1];
                float dz = a4.z - br[d4 * 4 + 2];
                float dw = a4.w - br[d4 * 4 + 3];
                acc += dx * dx + dy * dy + dz * dz + dw * dw;
            }
            out[((size_t)b * NN + pt * 16 + p) * NN + qt * 256 + t] = acc;
        }
    }
}

// Two rows' LSEs together (12 float4 loads in flight per wave).
// Returns natural-log LSE of (vec[j] - C_row[j]) / eps over j, both rows.
__device__ __forceinline__ float2 lse_pair(const float4* __restrict__ r0,
                                           const float4* __restrict__ r1,
                                           const float4* V4, int lane)
{
    float x0[16], x1[16];
#pragma unroll
    for (int k = 0; k < 4; ++k) {
        float4 c0 = r0[lane + (k << 6)];
        float4 c1 = r1[lane + (k << 6)];
        float4 v4 = V4[lane + (k << 6)];
        x0[4*k+0] = (v4.x - c0.x) * K2;
        x0[4*k+1] = (v4.y - c0.y) * K2;
        x0[4*k+2] = (v4.z - c0.z) * K2;
        x0[4*k+3] = (v4.w - c0.w) * K2;
        x1[4*k+0] = (v4.x - c1.x) * K2;
        x1[4*k+1] = (v4.y - c1.y) * K2;
        x1[4*k+2] = (v4.z - c1.z) * K2;
        x1[4*k+3] = (v4.w - c1.w) * K2;
    }
    float m0 = x0[0], m1 = x1[0];
#pragma unroll
    for (int i = 1; i < 16; ++i) { m0 = fmaxf(m0, x0[i]); m1 = fmaxf(m1, x1[i]); }
#pragma unroll
    for (int off = 32; off > 0; off >>= 1) {
        m0 = fmaxf(m0, __shfl_xor(m0, off));
        m1 = fmaxf(m1, __shfl_xor(m1, off));
    }
    float s0 = 0.f, s1 = 0.f;
#pragma unroll
    for (int i = 0; i < 16; ++i) { s0 += EXP2F(x0[i] - m0); s1 += EXP2F(x1[i] - m1); }
#pragma unroll
    for (int off = 32; off > 0; off >>= 1) {
        s0 += __shfl_xor(s0, off);
        s1 += __shfl_xor(s1, off);
    }
    return make_float2((m0 + LOG2F(s0)) * LN2f, (m1 + LOG2F(s1)) * LN2f);
}

// ---------------------------------------------------------------------------
// One Sinkhorn half-step (u-pass or v-pass) for iteration `it`.
// Grid 2048 x 256: block (b = blk>>7, l = blk&127) handles 8 rows (2/wave).
// First reconstructs the reference's `done` flag from the err table
// (done entering step it = any t' < it with mean_b err < 0.1) and returns
// without updating if set -> exact freeze semantics, no global sync needed
// (kernel boundaries order everything).
// ---------------------------------------------------------------------------
__global__ __launch_bounds__(256) void lse_pass(
    const float* __restrict__ Cmat,   // C (u-pass) or CT (v-pass)
    const float* __restrict__ vecin,  // v (u-pass) or u (v-pass)
    float* __restrict__ vecout,       // u (u-pass) or v (v-pass)
    float* __restrict__ err,          // err[16][128]
    int it, int do_err)
{
    __shared__ float ldsv[1024];
    __shared__ float red[4];
    __shared__ int s_done;
    const int tid = threadIdx.x, wave = tid >> 6, lane = tid & 63;
    const int b = blockIdx.x >> 7, l = blockIdx.x & 127;

    if (tid == 0) s_done = 0;
    __syncthreads();
    if (tid < it) {   // it <= 99 < 256
        float s = 0.f;
#pragma unroll
        for (int bb = 0; bb < 16; ++bb) s += err[(bb << 7) + tid];
        if (s < 1.6f) atomicOr(&s_done, 1);   // mean_b err < 0.1
    }
    ((float4*)ldsv)[tid] = ((const float4*)(vecin + (b << 10)))[tid];
    __syncthreads();
    if (s_done) return;   // frozen: vecout keeps its converged values

    const float* Cb  = Cmat + ((size_t)b << 20);
    float* outb = vecout + (b << 10);
    const int r = (l << 3) + (wave << 1);
    float2 lse = lse_pair((const float4*)(Cb + (size_t)r * NN),
                          (const float4*)(Cb + (size_t)(r + 1) * NN),
                          (const float4*)ldsv, lane);
    float werr = 0.f;
    if (lane == 0) {
        float n0 = EPSf * (LOGK - lse.x);
        float n1 = EPSf * (LOGK - lse.y);
        if (do_err) werr = fabsf(n0 - outb[r]) + fabsf(n1 - outb[r + 1]);
        outb[r]     = n0;
        outb[r + 1] = n1;
    }
    if (do_err) {
        if (lane == 0) red[wave] = werr;
        __syncthreads();
        if (tid == 0)
            atomicAdd(err + (b << 7) + it, red[0] + red[1] + red[2] + red[3]);
    }
}

// ---------------------------------------------------------------------------
// cost = mean_b sum_ij exp((u_i + v_j - C_ij)/eps) * C_ij
// ---------------------------------------------------------------------------
__global__ __launch_bounds__(256) void cost_kernel(
    const float* __restrict__ C, const float* __restrict__ u,
    const float* __restrict__ v, float* __restrict__ out)
{
    __shared__ float ldsv[1024];
    __shared__ float red[4];
    const int tid = threadIdx.x, wave = tid >> 6, lane = tid & 63;
    const int b = blockIdx.x >> 5, l = blockIdx.x & 31;

    ((float4*)ldsv)[tid] = ((const float4*)(v + (b << 10)))[tid];
    __syncthreads();

    const float* Cb = C + ((size_t)b << 20);
    const float* ub = u + (b << 10);
    float csum = 0.f;
    for (int rr = 0; rr < 8; ++rr) {
        const int row = (l << 5) + (wave << 3) + rr;
        const float ui = ub[row];
        const float4* Crow = (const float4*)(Cb + (size_t)row * NN);
        const float4* V4 = (const float4*)ldsv;
#pragma unroll
        for (int k = 0; k < 4; ++k) {
            float4 c4 = Crow[lane + (k << 6)];
            float4 v4 = V4[lane + (k << 6)];
            csum += EXP2F((ui + v4.x - c4.x) * K2) * c4.x;
            csum += EXP2F((ui + v4.y - c4.y) * K2) * c4.y;
            csum += EXP2F((ui + v4.z - c4.z) * K2) * c4.z;
            csum += EXP2F((ui + v4.w - c4.w) * K2) * c4.w;
        }
    }
#pragma unroll
    for (int off = 32; off > 0; off >>= 1) csum += __shfl_xor(csum, off);
    if (lane == 0) red[wave] = csum;
    __syncthreads();
    if (tid == 0)
        atomicAdd(out, (red[0] + red[1] + red[2] + red[3]) * (1.0f / 16.0f));
}

extern "C" void kernel_launch(void* const* d_in, const int* in_sizes, int n_in,
                              void* d_out, int out_size, void* d_ws, size_t ws_size,
                              hipStream_t stream) {
    const float* x = (const float*)d_in[0];  // output: [16,1024,32] fp32
    const float* y = (const float*)d_in[1];  // labels: [16,1024,32] fp32

    float* ws  = (float*)d_ws;
    float* C   = ws;                    // 16 M floats (64 MB)
    float* CT  = ws + 16777216;         // 16 M floats (64 MB)
    float* u   = ws + 33554432;         // 16384
    float* v   = u + 16384;             // 16384
    float* err = v + 16384;             // 16 x 128
    float* out = (float*)d_out;
    // total ws use: 134.36 MB  (<= round-1's proven footprint)

    // u, v, err are contiguous — zero them (+ out) every call (ws is poisoned)
    (void)hipMemsetAsync(u, 0, (size_t)(2 * 16384 + 2048) * sizeof(float), stream);
    (void)hipMemsetAsync(out, 0, sizeof(float), stream);

    build_dist<<<dim3(16 * 64), dim3(256), 0, stream>>>(x, y, C);
    build_dist<<<dim3(16 * 64), dim3(256), 0, stream>>>(y, x, CT);

    for (int it = 0; it < MAX_ITER; ++it) {
        lse_pass<<<dim3(2048), dim3(256), 0, stream>>>(C,  v, u, err, it, 1);
        lse_pass<<<dim3(2048), dim3(256), 0, stream>>>(CT, u, v, err, it, 0);
    }

    cost_kernel<<<dim3(512), dim3(256), 0, stream>>>(C, u, v, out);
}

// Round 7
// 1933.506 us; speedup vs baseline: 7.2201x; 1.3742x over previous
//
#include <hip/hip_runtime.h>

// Problem constants (B=16, N=M=1024, D=32)
constexpr int   NN       = 1024;
constexpr float EPSf     = 1e-3f;
constexpr int   MAX_ITER = 100;

// exp2-domain scale: x = (v - C) * (1/eps) * log2(e)
#define K2   1442.6950408889634f
#define LN2f 0.6931471805599453f
#define LOGK (-6.9314616f)   // log(1/1024 + 1e-8)

// hardware transcendentals (avoid libm name collisions)
#define EXP2F(x) __builtin_amdgcn_exp2f(x)   // 2^x
#define LOG2F(x) __builtin_amdgcn_logf(x)    // log2(x)

typedef _Float16 half8 __attribute__((ext_vector_type(8)));

// ---------------------------------------------------------------------------
// dist[b][p][q] = sum_d (A[b][p][d] - Bm[b][q][d])^2, stored fp16.
// build_dist(y,x) produces the bitwise-consistent transpose (same fp32 acc
// order), so C~ and C~^T are exact transposes of each other.
// ---------------------------------------------------------------------------
__global__ __launch_bounds__(256) void build_dist(
    const float* __restrict__ A, const float* __restrict__ Bm,
    _Float16* __restrict__ out)
{
    __shared__ float aLds[16 * 32];
    __shared__ float bLds[256 * 33];
    const int b  = blockIdx.x >> 6;       // 16 * 64 blocks
    const int pt = blockIdx.x & 63;
    const int t  = threadIdx.x;

    const float* Ab = A  + ((size_t)b * NN + pt * 16) * 32;
    const float* Bb = Bm + (size_t)b * NN * 32;

    if (t < 128) ((float4*)aLds)[t] = ((const float4*)Ab)[t];

    for (int qt = 0; qt < 4; ++qt) {
        __syncthreads();   // aLds ready (qt=0) / bLds reuse safe (qt>0)
        const float4* src = (const float4*)(Bb + qt * 256 * 32);
#pragma unroll
        for (int i = 0; i < 8; ++i) {
            int j = t + (i << 8);                 // float4 index, coalesced
            float4 val = src[j];
            int q = j >> 3, dd = (j & 7) << 2;
            float* dst = &bLds[q * 33 + dd];
            dst[0] = val.x; dst[1] = val.y; dst[2] = val.z; dst[3] = val.w;
        }
        __syncthreads();

        float br[32];
#pragma unroll
        for (int d = 0; d < 32; ++d) br[d] = bLds[t * 33 + d];

#pragma unroll
        for (int p = 0; p < 16; ++p) {
            float acc = 0.f;
#pragma unroll
            for (int d4 = 0; d4 < 8; ++d4) {
                float4 a4 = ((const float4*)(aLds + p * 32))[d4];
                float dx = a4.x - br[d4 * 4 + 0];
                float dy = a4.y - br[d4 * 4 + 1];
                float dz = a4.z - br[d4 * 4 + 2];
                float dw = a4.w - br[d4 * 4 + 3];
                acc += dx * dx + dy * dy + dz * dz + dw * dw;
            }
            out[((size_t)b * NN + pt * 16 + p) * NN + qt * 256 + t] = (_Float16)acc;
        }
    }
}

// Two rows' LSEs together from fp16 rows (16 B/lane half8 loads).
// Returns natural-log LSE of (vec[j] - C_row[j]) / eps over j, both rows.
__device__ __forceinline__ float2 lse_pair_h(const half8* __restrict__ r0,
                                             const half8* __restrict__ r1,
                                             const float4* V4, int lane)
{
    float x0[16], x1[16];
#pragma unroll
    for (int k = 0; k < 2; ++k) {
        const int m = lane + (k << 6);
        half8 c0 = r0[m];
        half8 c1 = r1[m];
        float4 va = V4[2 * m];
        float4 vb = V4[2 * m + 1];
        float vv[8] = {va.x, va.y, va.z, va.w, vb.x, vb.y, vb.z, vb.w};
#pragma unroll
        for (int j = 0; j < 8; ++j) {
            x0[8 * k + j] = (vv[j] - (float)c0[j]) * K2;
            x1[8 * k + j] = (vv[j] - (float)c1[j]) * K2;
        }
    }
    float m0 = x0[0], m1 = x1[0];
#pragma unroll
    for (int i = 1; i < 16; ++i) { m0 = fmaxf(m0, x0[i]); m1 = fmaxf(m1, x1[i]); }
#pragma unroll
    for (int off = 32; off > 0; off >>= 1) {
        m0 = fmaxf(m0, __shfl_xor(m0, off));
        m1 = fmaxf(m1, __shfl_xor(m1, off));
    }
    float s0 = 0.f, s1 = 0.f;
#pragma unroll
    for (int i = 0; i < 16; ++i) { s0 += EXP2F(x0[i] - m0); s1 += EXP2F(x1[i] - m1); }
#pragma unroll
    for (int off = 32; off > 0; off >>= 1) {
        s0 += __shfl_xor(s0, off);
        s1 += __shfl_xor(s1, off);
    }
    return make_float2((m0 + LOG2F(s0)) * LN2f, (m1 + LOG2F(s1)) * LN2f);
}

// ---------------------------------------------------------------------------
// One Sinkhorn half-step (u-pass or v-pass) for iteration `it`.
// Grid 2048 x 256: block (b = blk>>7, l = blk&127) handles 8 rows (2/wave).
// Reconstructs the reference's `done` flag from the err table and freezes.
// ---------------------------------------------------------------------------
__global__ __launch_bounds__(256) void lse_pass(
    const _Float16* __restrict__ Cmat,  // C (u-pass) or CT (v-pass), fp16
    const float* __restrict__ vecin,    // v (u-pass) or u (v-pass)
    float* __restrict__ vecout,         // u (u-pass) or v (v-pass)
    float* __restrict__ err,            // err[16][128]
    int it, int do_err)
{
    __shared__ float ldsv[1024];
    __shared__ float red[4];
    __shared__ int s_done;
    const int tid = threadIdx.x, wave = tid >> 6, lane = tid & 63;
    const int b = blockIdx.x >> 7, l = blockIdx.x & 127;

    if (tid == 0) s_done = 0;
    __syncthreads();
    if (tid < it) {   // it <= 99 < 256
        float s = 0.f;
#pragma unroll
        for (int bb = 0; bb < 16; ++bb) s += err[(bb << 7) + tid];
        if (s < 1.6f) atomicOr(&s_done, 1);   // mean_b err < 0.1
    }
    ((float4*)ldsv)[tid] = ((const float4*)(vecin + (b << 10)))[tid];
    __syncthreads();
    if (s_done) return;   // frozen: vecout keeps its converged values

    const _Float16* Cb = Cmat + ((size_t)b << 20);
    float* outb = vecout + (b << 10);
    const int r = (l << 3) + (wave << 1);
    float2 lse = lse_pair_h((const half8*)(Cb + (size_t)r * NN),
                            (const half8*)(Cb + (size_t)(r + 1) * NN),
                            (const float4*)ldsv, lane);
    float werr = 0.f;
    if (lane == 0) {
        float n0 = EPSf * (LOGK - lse.x);
        float n1 = EPSf * (LOGK - lse.y);
        if (do_err) werr = fabsf(n0 - outb[r]) + fabsf(n1 - outb[r + 1]);
        outb[r]     = n0;
        outb[r + 1] = n1;
    }
    if (do_err) {
        if (lane == 0) red[wave] = werr;
        __syncthreads();
        if (tid == 0)
            atomicAdd(err + (b << 7) + it, red[0] + red[1] + red[2] + red[3]);
    }
}

// ---------------------------------------------------------------------------
// cost = mean_b sum_ij exp((u_i + v_j - C_ij)/eps) * C_ij   (fp16 C)
// ---------------------------------------------------------------------------
__global__ __launch_bounds__(256) void cost_kernel(
    const _Float16* __restrict__ C, const float* __restrict__ u,
    const float* __restrict__ v, float* __restrict__ out)
{
    __shared__ float ldsv[1024];
    __shared__ float red[4];
    const int tid = threadIdx.x, wave = tid >> 6, lane = tid & 63;
    const int b = blockIdx.x >> 5, l = blockIdx.x & 31;

    ((float4*)ldsv)[tid] = ((const float4*)(v + (b << 10)))[tid];
    __syncthreads();

    const _Float16* Cb = C + ((size_t)b << 20);
    const float* ub = u + (b << 10);
    const float4* V4 = (const float4*)ldsv;
    float csum = 0.f;
    for (int rr = 0; rr < 8; ++rr) {
        const int row = (l << 5) + (wave << 3) + rr;
        const float ui = ub[row];
        const half8* Crow = (const half8*)(Cb + (size_t)row * NN);
#pragma unroll
        for (int k = 0; k < 2; ++k) {
            const int m = lane + (k << 6);
            half8 c8 = Crow[m];
            float4 va = V4[2 * m];
            float4 vb = V4[2 * m + 1];
            float vv[8] = {va.x, va.y, va.z, va.w, vb.x, vb.y, vb.z, vb.w};
#pragma unroll
            for (int j = 0; j < 8; ++j) {
                float c = (float)c8[j];
                csum += EXP2F((ui + vv[j] - c) * K2) * c;
            }
        }
    }
#pragma unroll
    for (int off = 32; off > 0; off >>= 1) csum += __shfl_xor(csum, off);
    if (lane == 0) red[wave] = csum;
    __syncthreads();
    if (tid == 0)
        atomicAdd(out, (red[0] + red[1] + red[2] + red[3]) * (1.0f / 16.0f));
}

extern "C" void kernel_launch(void* const* d_in, const int* in_sizes, int n_in,
                              void* d_out, int out_size, void* d_ws, size_t ws_size,
                              hipStream_t stream) {
    const float* x = (const float*)d_in[0];  // output: [16,1024,32] fp32
    const float* y = (const float*)d_in[1];  // labels: [16,1024,32] fp32

    char* wsb = (char*)d_ws;
    _Float16* C  = (_Float16*)wsb;                   // 16 M halves (32 MB)
    _Float16* CT = (_Float16*)(wsb + 33554432);      // 16 M halves (32 MB)
    float* u   = (float*)(wsb + 67108864);           // 16384
    float* v   = u + 16384;                          // 16384
    float* err = v + 16384;                          // 16 x 128
    float* out = (float*)d_out;

    // u, v, err contiguous — zero them (+ out) every call (ws is poisoned)
    (void)hipMemsetAsync(u, 0, (size_t)(2 * 16384 + 2048) * sizeof(float), stream);
    (void)hipMemsetAsync(out, 0, sizeof(float), stream);

    build_dist<<<dim3(16 * 64), dim3(256), 0, stream>>>(x, y, C);
    build_dist<<<dim3(16 * 64), dim3(256), 0, stream>>>(y, x, CT);

    for (int it = 0; it < MAX_ITER; ++it) {
        lse_pass<<<dim3(2048), dim3(256), 0, stream>>>(C,  v, u, err, it, 1);
        lse_pass<<<dim3(2048), dim3(256), 0, stream>>>(CT, u, v, err, it, 0);
    }

    cost_kernel<<<dim3(512), dim3(256), 0, stream>>>(C, u, v, out);
}

// Round 8
// 1825.726 us; speedup vs baseline: 7.6463x; 1.0590x over previous
//
#include <hip/hip_runtime.h>

// Problem constants (B=16, N=M=1024, D=32)
constexpr int   NN       = 1024;
constexpr float EPSf     = 1e-3f;
constexpr int   MAX_ITER = 100;

// exp2-domain scale: x = (v - C) * (1/eps) * log2(e)
#define K2      1442.6950408889634f
#define LN2f    0.6931471805599453f
#define INV_LN2 1.4426950408889634f
#define INV_EPS 1000.0f
#define LOGK    (-6.9314616f)   // log(1/1024 + 1e-8)

// hardware transcendentals (avoid libm name collisions)
#define EXP2F(x) __builtin_amdgcn_exp2f(x)   // 2^x
#define LOG2F(x) __builtin_amdgcn_logf(x)    // log2(x)

typedef _Float16 half8 __attribute__((ext_vector_type(8)));

// ---------------------------------------------------------------------------
// dist[b][p][q] = sum_d (A[b][p][d] - Bm[b][q][d])^2, stored fp16.
// build_dist(y,x) produces the bitwise-consistent transpose.
// ---------------------------------------------------------------------------
__global__ __launch_bounds__(256) void build_dist(
    const float* __restrict__ A, const float* __restrict__ Bm,
    _Float16* __restrict__ out)
{
    __shared__ float aLds[16 * 32];
    __shared__ float bLds[256 * 33];
    const int b  = blockIdx.x >> 6;       // 16 * 64 blocks
    const int pt = blockIdx.x & 63;
    const int t  = threadIdx.x;

    const float* Ab = A  + ((size_t)b * NN + pt * 16) * 32;
    const float* Bb = Bm + (size_t)b * NN * 32;

    if (t < 128) ((float4*)aLds)[t] = ((const float4*)Ab)[t];

    for (int qt = 0; qt < 4; ++qt) {
        __syncthreads();
        const float4* src = (const float4*)(Bb + qt * 256 * 32);
#pragma unroll
        for (int i = 0; i < 8; ++i) {
            int j = t + (i << 8);
            float4 val = src[j];
            int q = j >> 3, dd = (j & 7) << 2;
            float* dst = &bLds[q * 33 + dd];
            dst[0] = val.x; dst[1] = val.y; dst[2] = val.z; dst[3] = val.w;
        }
        __syncthreads();

        float br[32];
#pragma unroll
        for (int d = 0; d < 32; ++d) br[d] = bLds[t * 33 + d];

#pragma unroll
        for (int p = 0; p < 16; ++p) {
            float acc = 0.f;
#pragma unroll
            for (int d4 = 0; d4 < 8; ++d4) {
                float4 a4 = ((const float4*)(aLds + p * 32))[d4];
                float dx = a4.x - br[d4 * 4 + 0];
                float dy = a4.y - br[d4 * 4 + 1];
                float dz = a4.z - br[d4 * 4 + 2];
                float dw = a4.w - br[d4 * 4 + 3];
                acc += dx * dx + dy * dy + dz * dz + dw * dw;
            }
            out[((size_t)b * NN + pt * 16 + p) * NN + qt * 256 + t] = (_Float16)acc;
        }
    }
}

// ---------------------------------------------------------------------------
// One Sinkhorn half-step. Grid 2048 x 256: block (b=blk>>7, l=blk&127)
// handles 8 rows (2/wave). Fast path: exp2 shifted by the PREVIOUS
// iterate's LSE (M from u_old) — no max pass. Wave-uniform guard falls
// back to classic max-shifted LSE on under/overflow (all rows at it=0).
// Freeze flag is a precomputed chain: dflag[it] read by all blocks;
// v-pass block 0 writes dflag[it+1] from err[.][it].
// ---------------------------------------------------------------------------
__global__ __launch_bounds__(256) void lse_pass(
    const _Float16* __restrict__ Cmat,  // C (u-pass) or CT (v-pass), fp16
    const float* __restrict__ vecin,    // v (u-pass) or u (v-pass)
    float* __restrict__ vecout,         // u (u-pass) or v (v-pass)
    float* __restrict__ err,            // err[16][128]
    int* __restrict__ dflag,            // dflag[101]
    int it, int do_err)
{
    __shared__ float ldsvk[1024];
    __shared__ float red[4];
    __shared__ int s_done;
    const int tid = threadIdx.x, wave = tid >> 6, lane = tid & 63;
    const int b = blockIdx.x >> 7, l = blockIdx.x & 127;

    // maintain the freeze chain (v-pass only; err[.][it] complete from u-pass)
    if (!do_err && blockIdx.x == 0 && tid < 16) {
        float e = err[(tid << 7) + it];
        e += __shfl_xor(e, 1); e += __shfl_xor(e, 2);
        e += __shfl_xor(e, 4); e += __shfl_xor(e, 8);
        if (tid == 0) dflag[it + 1] = dflag[it] | (e < 1.6f ? 1 : 0);
    }
    if (tid == 0) s_done = dflag[it];
    {   // stage vk = vecin * K2
        float4 t = ((const float4*)(vecin + (b << 10)))[tid];
        t.x *= K2; t.y *= K2; t.z *= K2; t.w *= K2;
        ((float4*)ldsvk)[tid] = t;
    }
    __syncthreads();
    if (s_done) return;   // frozen: vecout keeps its converged values

    const _Float16* Cb = Cmat + ((size_t)b << 20);
    float* outb = vecout + (b << 10);
    const int r = (l << 3) + (wave << 1);

    const half8* r0 = (const half8*)(Cb + (size_t)r * NN);
    const half8* r1 = (const half8*)(Cb + (size_t)(r + 1) * NN);
    const float4* V4 = (const float4*)ldsvk;

    const float uo0 = outb[r], uo1 = outb[r + 1];
    const float M0 = (LOGK - uo0 * INV_EPS) * INV_LN2;
    const float M1 = (LOGK - uo1 * INV_EPS) * INV_LN2;

    float x0[16], x1[16];
#pragma unroll
    for (int k = 0; k < 2; ++k) {
        const int m_ = lane + (k << 6);
        half8 c0 = r0[m_];
        half8 c1 = r1[m_];
        float4 va = V4[2 * m_], vb = V4[2 * m_ + 1];
        float vv[8] = {va.x, va.y, va.z, va.w, vb.x, vb.y, vb.z, vb.w};
#pragma unroll
        for (int j = 0; j < 8; ++j) {
            x0[8 * k + j] = fmaf((float)c0[j], -K2, vv[j]);
            x1[8 * k + j] = fmaf((float)c1[j], -K2, vv[j]);
        }
    }
    float s0 = 0.f, s1 = 0.f;
#pragma unroll
    for (int i = 0; i < 16; ++i) {
        s0 += EXP2F(x0[i] - M0);
        s1 += EXP2F(x1[i] - M1);
    }
#pragma unroll
    for (int off = 32; off > 0; off >>= 1) {
        s0 += __shfl_xor(s0, off);
        s1 += __shfl_xor(s1, off);
    }

    float lse2_0, lse2_1;
    if (__builtin_expect(!(s0 >= 1e-27f && s0 <= 1e38f) ||
                         !(s1 >= 1e-27f && s1 <= 1e38f), 0)) {
        // fallback: classic max-shifted LSE (fires at it=0 and on drift)
        float m0 = x0[0], m1 = x1[0];
#pragma unroll
        for (int i = 1; i < 16; ++i) { m0 = fmaxf(m0, x0[i]); m1 = fmaxf(m1, x1[i]); }
#pragma unroll
        for (int off = 32; off > 0; off >>= 1) {
            m0 = fmaxf(m0, __shfl_xor(m0, off));
            m1 = fmaxf(m1, __shfl_xor(m1, off));
        }
        float t0 = 0.f, t1 = 0.f;
#pragma unroll
        for (int i = 0; i < 16; ++i) { t0 += EXP2F(x0[i] - m0); t1 += EXP2F(x1[i] - m1); }
#pragma unroll
        for (int off = 32; off > 0; off >>= 1) {
            t0 += __shfl_xor(t0, off);
            t1 += __shfl_xor(t1, off);
        }
        lse2_0 = m0 + LOG2F(t0);
        lse2_1 = m1 + LOG2F(t1);
    } else {
        lse2_0 = M0 + LOG2F(s0);
        lse2_1 = M1 + LOG2F(s1);
    }

    float werr = 0.f;
    if (lane == 0) {
        float n0 = EPSf * (LOGK - lse2_0 * LN2f);
        float n1 = EPSf * (LOGK - lse2_1 * LN2f);
        if (do_err) werr = fabsf(n0 - uo0) + fabsf(n1 - uo1);
        outb[r]     = n0;
        outb[r + 1] = n1;
    }
    if (do_err) {
        if (lane == 0) red[wave] = werr;
        __syncthreads();
        if (tid == 0)
            atomicAdd(err + (b << 7) + it, red[0] + red[1] + red[2] + red[3]);
    }
}

// ---------------------------------------------------------------------------
// cost = mean_b sum_ij exp((u_i + v_j - C_ij)/eps) * C_ij   (fp16 C)
// ---------------------------------------------------------------------------
__global__ __launch_bounds__(256) void cost_kernel(
    const _Float16* __restrict__ C, const float* __restrict__ u,
    const float* __restrict__ v, float* __restrict__ out)
{
    __shared__ float ldsv[1024];
    __shared__ float red[4];
    const int tid = threadIdx.x, wave = tid >> 6, lane = tid & 63;
    const int b = blockIdx.x >> 5, l = blockIdx.x & 31;

    ((float4*)ldsv)[tid] = ((const float4*)(v + (b << 10)))[tid];
    __syncthreads();

    const _Float16* Cb = C + ((size_t)b << 20);
    const float* ub = u + (b << 10);
    const float4* V4 = (const float4*)ldsv;
    float csum = 0.f;
    for (int rr = 0; rr < 8; ++rr) {
        const int row = (l << 5) + (wave << 3) + rr;
        const float ui = ub[row];
        const half8* Crow = (const half8*)(Cb + (size_t)row * NN);
#pragma unroll
        for (int k = 0; k < 2; ++k) {
            const int m = lane + (k << 6);
            half8 c8 = Crow[m];
            float4 va = V4[2 * m];
            float4 vb = V4[2 * m + 1];
            float vv[8] = {va.x, va.y, va.z, va.w, vb.x, vb.y, vb.z, vb.w};
#pragma unroll
            for (int j = 0; j < 8; ++j) {
                float c = (float)c8[j];
                csum += EXP2F((ui + vv[j] - c) * K2) * c;
            }
        }
    }
#pragma unroll
    for (int off = 32; off > 0; off >>= 1) csum += __shfl_xor(csum, off);
    if (lane == 0) red[wave] = csum;
    __syncthreads();
    if (tid == 0)
        atomicAdd(out, (red[0] + red[1] + red[2] + red[3]) * (1.0f / 16.0f));
}

extern "C" void kernel_launch(void* const* d_in, const int* in_sizes, int n_in,
                              void* d_out, int out_size, void* d_ws, size_t ws_size,
                              hipStream_t stream) {
    const float* x = (const float*)d_in[0];  // output: [16,1024,32] fp32
    const float* y = (const float*)d_in[1];  // labels: [16,1024,32] fp32

    char* wsb = (char*)d_ws;
    _Float16* C  = (_Float16*)wsb;                   // 16 M halves (32 MB)
    _Float16* CT = (_Float16*)(wsb + 33554432);      // 16 M halves (32 MB)
    float* u     = (float*)(wsb + 67108864);         // 16384
    float* v     = u + 16384;                        // 16384
    float* err   = v + 16384;                        // 16 x 128
    int*   dflag = (int*)(err + 2048);               // 128
    float* out   = (float*)d_out;

    // u, v, err, dflag contiguous — zero them (+ out) every call
    (void)hipMemsetAsync(u, 0, (size_t)(2 * 16384 + 2048 + 128) * 4, stream);
    (void)hipMemsetAsync(out, 0, sizeof(float), stream);

    build_dist<<<dim3(16 * 64), dim3(256), 0, stream>>>(x, y, C);
    build_dist<<<dim3(16 * 64), dim3(256), 0, stream>>>(y, x, CT);

    for (int it = 0; it < MAX_ITER; ++it) {
        lse_pass<<<dim3(2048), dim3(256), 0, stream>>>(C,  v, u, err, dflag, it, 1);
        lse_pass<<<dim3(2048), dim3(256), 0, stream>>>(CT, u, v, err, dflag, it, 0);
    }

    cost_kernel<<<dim3(512), dim3(256), 0, stream>>>(C, u, v, out);
}